// Round 8
// baseline (470.875 us; speedup 1.0000x reference)
//
#include <hip/hip_runtime.h>

// EGNN fused layer, MI355X gfx950 — v9 (128-edge tiles: halve per-tile structure).
// out[0 : 50000*64)          = h + segment_sum(node messages, dst)
// out[50000*64 : +50000*3)   = x + segment_sum(coord updates, dst)
//
// v8 post-mortem: FETCH halved -> -2%.  4th falsified single-pipe theory.
// Residual: ~16.4k cyc/CU per 64-edge tile vs ~6k of countable pipe work ->
// per-tile FIXED cost (3 barrier convoys, phase ramps) dominates.
// Changes vs v8:
//  - 128-edge tiles, 256 threads: half the barriers/iterations per edge.
//    Each wave: 8 M-tiles; GEMM1 split N-pass/C-pass (v5-proven, caps live
//    acc at 64 regs); GEMM2 8 mt.  LDS 81.2 KB -> still 2 blocks/CU.
//  - indices-only prefetch; h rows direct-gathered from L2-resident bf16
//    table in the stage phase (16 independent loads, one latency).
//  - keeps: bf16 h table, pi-packed hl, 3 lgkm-only barriers/tile, direct
//    atomic epilogue, folded We2/be2, x prefetch at stage.

#define NN 50000
#define NE 800000
#define NDIM 64
#define HDIM 128
#define TEDGE 128
#define NTILES (NE / TEDGE)   // 6250, exact
#define MSTRIDE 168           // m_input LDS row stride (ushorts): 160 + 8 pad
#define HSTRIDE 136           // hidden LDS row stride (ushorts): 128 + 8 pad
#define NH (NN * NDIM)        // 3,200,000
#define NX (NN * 3)           // 150,000

// workspace layout (identical to v8)
#define WS_WN1P 0             // [160][128] floats
#define WS_WC1P 20480
#define WS_BN1P 40960
#define WS_BC1P 41088
#define WS_HBF_OFF 65536      // float offset -> hbf (ushort*)

typedef __bf16 bf16x8 __attribute__((ext_vector_type(8)));
typedef float f32x4 __attribute__((ext_vector_type(4)));
typedef unsigned short ushort8 __attribute__((ext_vector_type(8)));
typedef unsigned short ushort4v __attribute__((ext_vector_type(4)));

__device__ __forceinline__ unsigned short f2bf(float f) {
    union { __bf16 b; unsigned short u; } c;
    c.b = (__bf16)f;
    return c.u;
}
__device__ __forceinline__ float silu(float v) {
    return __fdividef(v, 1.0f + __expf(-v));
}
// lgkm-only barrier: all cross-thread deps flow through LDS; atomics and
// prefetch loads stay in flight across it.
__device__ __forceinline__ void bar_lds() {
    asm volatile("s_waitcnt lgkmcnt(0)" ::: "memory");
    __builtin_amdgcn_s_barrier();
}
__device__ __forceinline__ bf16x8 ld_frag(const unsigned short* p) {
    union { ushort8 u; bf16x8 v; } c;
    c.u = *(const ushort8*)p;
    return c.v;
}
__device__ __forceinline__ bf16x8 mk_frag(const unsigned short* u) {
    union { ushort8 uu; bf16x8 v; } c;
#pragma unroll
    for (int j = 0; j < 8; ++j) c.uu[j] = u[j];
    return c.v;
}

// 16-value butterfly sum over the 16-lane l15 group; lane l15 returns the
// group total of p[l15].  (v8-proven pattern.)
__device__ __forceinline__ float butterfly16(const float* p, int l15) {
    float q8[8];
#pragma unroll
    for (int i = 0; i < 8; ++i) {
        const float send = (l15 & 8) ? p[i] : p[i + 8];
        const float recv = __shfl_xor(send, 8, 64);
        q8[i] = ((l15 & 8) ? p[i + 8] : p[i]) + recv;
    }
    float q4[4];
#pragma unroll
    for (int i = 0; i < 4; ++i) {
        const float send = (l15 & 4) ? q8[i] : q8[i + 4];
        const float recv = __shfl_xor(send, 4, 64);
        q4[i] = ((l15 & 4) ? q8[i + 4] : q8[i]) + recv;
    }
    float q2[2];
#pragma unroll
    for (int i = 0; i < 2; ++i) {
        const float send = (l15 & 2) ? q4[i] : q4[i + 2];
        const float recv = __shfl_xor(send, 2, 64);
        q2[i] = ((l15 & 2) ? q4[i + 2] : q4[i]) + recv;
    }
    const float send = (l15 & 1) ? q2[0] : q2[1];
    const float recv = __shfl_xor(send, 1, 64);
    return ((l15 & 1) ? q2[1] : q2[0]) + recv;
}

// ---- prep: fold weights -> ws, init out, build bf16 h table (v8, unchanged) ----
__global__ __launch_bounds__(256) void prep(
    const float* __restrict__ h, const float* __restrict__ x,
    const float* __restrict__ We2, const float* __restrict__ be2,
    const float* __restrict__ Wn1, const float* __restrict__ bn1,
    const float* __restrict__ Wc1, const float* __restrict__ bc1,
    float* __restrict__ out, float* __restrict__ wsf) {
    const int gtid = blockIdx.x * 256 + threadIdx.x;
    const int G = gridDim.x * 256;

    if (gtid < 41216) {
        if (gtid < 40960) {
            const int path = gtid / 20480;
            const int rem = gtid - path * 20480;
            const int r = rem >> 7, col = rem & 127;
            const float* W = path ? Wc1 : Wn1;
            float* Wp = wsf + (path ? WS_WC1P : WS_WN1P);
            if (r < 128) {
                Wp[r * 128 + col] = W[r * 128 + col];
            } else {
                const int j = r - 128;
                float s = 0.0f;
#pragma unroll
                for (int n = 0; n < 32; ++n)
                    s += We2[j * 32 + n] * W[(128 + n) * 128 + col];
                Wp[r * 128 + col] = s;
            }
        } else {
            const int j = gtid - 40960;
            const int path = j >> 7, col = j & 127;
            const float* W = path ? Wc1 : Wn1;
            const float* bb = path ? bc1 : bn1;
            float s = bb[col];
#pragma unroll
            for (int n = 0; n < 32; ++n)
                s += be2[n] * W[(128 + n) * 128 + col];
            wsf[(path ? WS_BC1P : WS_BN1P) + col] = s;
        }
    }

    unsigned short* hbf = (unsigned short*)(wsf + WS_HBF_OFF);
    const float4* h4 = (const float4*)h;
    float4* out4 = (float4*)out;
    for (int i = gtid; i < NH / 4; i += G) {
        const float4 v = h4[i];
        out4[i] = v;
        ushort4v u = { f2bf(v.x), f2bf(v.y), f2bf(v.z), f2bf(v.w) };
        *(ushort4v*)&hbf[i * 4] = u;
    }
    for (int i = gtid; i < NX; i += G) out[NH + i] = x[i];
}

// ---- main fused kernel: 128-edge tiles ----
__global__ __launch_bounds__(256, 2) void egnn_edges(
    const float* __restrict__ x,
    const int* __restrict__ srcg, const int* __restrict__ dstg,
    const float* __restrict__ dist,
    const float* __restrict__ We1, const float* __restrict__ be1,
    const float* __restrict__ Wn2, const float* __restrict__ bn2,
    const float* __restrict__ Wc2,
    const float* __restrict__ wsW,
    float* __restrict__ outh, float* __restrict__ outx) {

    __shared__ __align__(16) unsigned short mlds[TEDGE * MSTRIDE];  // 43,008 B
    __shared__ __align__(16) unsigned short hl[TEDGE * HSTRIDE];    // 34,816 B
    __shared__ int src_l[TEDGE];
    __shared__ int dst_l[TEDGE];
    __shared__ float we1_l[32], be1_l[32];
    __shared__ float part_l[4 * TEDGE];                             // 2,048 B

    const int tid  = threadIdx.x;
    const int w    = tid >> 6;        // wave 0..3 (col group)
    const int lane = tid & 63;
    const int l15  = lane & 15;
    const int quad = lane >> 4;
    const int c4   = tid & 15, sub16 = tid >> 4;   // staging geometry

    const unsigned short* hbf = (const unsigned short*)(wsW + WS_HBF_OFF);
    const float* Wn1p = wsW + WS_WN1P;
    const float* Wc1p = wsW + WS_WC1P;
    const float* bn1p = wsW + WS_BN1P;
    const float* bc1p = wsW + WS_BC1P;

    if (tid < 32) { we1_l[tid] = We1[tid]; be1_l[tid] = be1[tid]; }

    // ---- one-time: B-fragments from folded weights (per v8) ----
    bf16x8 wn1f[5][2], wc1f[5][2];
#pragma unroll
    for (int kc = 0; kc < 5; ++kc) {
#pragma unroll
        for (int nt = 0; nt < 2; ++nt) {
            unsigned short un[8], uc[8];
            const int n = w * 32 + nt * 16 + l15;
#pragma unroll
            for (int j = 0; j < 8; ++j) {
                const int k = kc * 32 + quad * 8 + j;
                un[j] = f2bf(Wn1p[k * HDIM + n]);
                uc[j] = f2bf(Wc1p[k * HDIM + n]);
            }
            wn1f[kc][nt] = mk_frag(un);
            wc1f[kc][nt] = mk_frag(uc);
        }
    }
    // GEMM2 B-frags, pi-permuted k (matches packed hl): D(k) = (k&~31)+((k&1)<<4)+((k&31)>>1)
    bf16x8 wn2f[4];
#pragma unroll
    for (int kc = 0; kc < 4; ++kc) {
        unsigned short u[8];
        const int n = w * 16 + l15;
#pragma unroll
        for (int j = 0; j < 8; ++j) {
            const int k = kc * 32 + quad * 8 + j;
            const int D = (k & ~31) + ((k & 1) << 4) + ((k & 31) >> 1);
            u[j] = f2bf(Wn2[D * NDIM + n]);
        }
        wn2f[kc] = mk_frag(u);
    }
    const float biasN0 = bn1p[w * 32 + l15];
    const float biasN1 = bn1p[w * 32 + 16 + l15];
    const float biasC0 = bc1p[w * 32 + l15];
    const float biasC1 = bc1p[w * 32 + 16 + l15];
    const float bias2v = bn2[w * 16 + l15];
    const float wcA = Wc2[w * 32 + l15];
    const float wcB = Wc2[w * 32 + 16 + l15];

    // ---- prologue prefetch: indices + dist + epilogue indices ----
    int psn[8], pdn[8];
    float pdist;
    int psl = 0, pdl = 0;
    {
        const int e0 = blockIdx.x * TEDGE;
#pragma unroll
        for (int it = 0; it < 8; ++it) {
            psn[it] = srcg[e0 + sub16 + it * 16];
            pdn[it] = dstg[e0 + sub16 + it * 16];
        }
        pdist = dist[e0 + (tid >> 1)];
        if (tid < 128) { psl = srcg[e0 + tid]; pdl = dstg[e0 + tid]; }
    }

    for (int tile = blockIdx.x; tile < NTILES; tile += gridDim.x) {
        bar_lds();   // (1) previous tile's LDS reads all done

        // ---- stage: indices to LDS, x epilogue loads, h-row gathers, s ----
        float xs0 = 0, xs1 = 0, xs2 = 0, xd0 = 0, xd1 = 0, xd2 = 0;
        if (tid < 128) {
            src_l[tid] = psl; dst_l[tid] = pdl;
            xs0 = x[psl * 3 + 0]; xs1 = x[psl * 3 + 1]; xs2 = x[psl * 3 + 2];
            xd0 = x[pdl * 3 + 0]; xd1 = x[pdl * 3 + 1]; xd2 = x[pdl * 3 + 2];
        }
        {
            // 16 independent gathers from L2-resident bf16 table, then write
            ushort4v us[8], ud[8];
#pragma unroll
            for (int it = 0; it < 8; ++it) {
                us[it] = *(const ushort4v*)(hbf + (size_t)psn[it] * NDIM + c4 * 4);
                ud[it] = *(const ushort4v*)(hbf + (size_t)pdn[it] * NDIM + c4 * 4);
            }
#pragma unroll
            for (int it = 0; it < 8; ++it) {
                const int el = sub16 + it * 16;
                *(ushort4v*)&mlds[el * MSTRIDE + c4 * 4] = us[it];
                *(ushort4v*)&mlds[el * MSTRIDE + 64 + c4 * 4] = ud[it];
            }
        }
        {
            const int el = tid >> 1, j0 = (tid & 1) * 16;
            ushort8 ua, ub;
#pragma unroll
            for (int j = 0; j < 8; ++j)
                ua[j] = f2bf(silu(pdist * we1_l[j0 + j] + be1_l[j0 + j]));
#pragma unroll
            for (int j = 0; j < 8; ++j)
                ub[j] = f2bf(silu(pdist * we1_l[j0 + 8 + j] + be1_l[j0 + 8 + j]));
            *(ushort8*)&mlds[el * MSTRIDE + 128 + j0] = ua;
            *(ushort8*)&mlds[el * MSTRIDE + 128 + j0 + 8] = ub;
        }
        bar_lds();   // (2) m_input ready

        // ---- prefetch next tile's indices (lands under GEMM1) ----
        {
            const int tn = tile + (int)gridDim.x;
            const int eb = (tn < NTILES ? tn : tile) * TEDGE;
#pragma unroll
            for (int it = 0; it < 8; ++it) {
                psn[it] = srcg[eb + sub16 + it * 16];
                pdn[it] = dstg[eb + sub16 + it * 16];
            }
            pdist = dist[eb + (tid >> 1)];
            if (tid < 128) { psl = srcg[eb + tid]; pdl = dstg[eb + tid]; }
        }

        // ---- GEMM1 N-pass: [128x160] @ Wn1' ; silu -> hl (packed, pi cols) ----
        {
            f32x4 accN[8][2];
#pragma unroll
            for (int mt = 0; mt < 8; ++mt) {
                accN[mt][0] = (f32x4){biasN0, biasN0, biasN0, biasN0};
                accN[mt][1] = (f32x4){biasN1, biasN1, biasN1, biasN1};
            }
#pragma unroll
            for (int kc = 0; kc < 5; ++kc) {
#pragma unroll
                for (int mt = 0; mt < 8; ++mt) {
                    bf16x8 af = ld_frag(&mlds[(mt * 16 + l15) * MSTRIDE + kc * 32 + quad * 8]);
                    accN[mt][0] = __builtin_amdgcn_mfma_f32_16x16x32_bf16(af, wn1f[kc][0], accN[mt][0], 0, 0, 0);
                    accN[mt][1] = __builtin_amdgcn_mfma_f32_16x16x32_bf16(af, wn1f[kc][1], accN[mt][1], 0, 0, 0);
                }
            }
            unsigned int* hlu = (unsigned int*)hl;
#pragma unroll
            for (int mt = 0; mt < 8; ++mt)
#pragma unroll
                for (int r = 0; r < 4; ++r) {
                    const unsigned int u0 = f2bf(silu(accN[mt][0][r]));
                    const unsigned int u1 = f2bf(silu(accN[mt][1][r]));
                    hlu[(mt * 16 + quad * 4 + r) * (HSTRIDE / 2) + w * 16 + l15] =
                        (u1 << 16) | u0;
                }
        }

        // ---- GEMM1 C-pass: [128x160] @ Wc1' ; silu*Wc2 + 2x butterfly ----
        {
            f32x4 accC[8][2];
#pragma unroll
            for (int mt = 0; mt < 8; ++mt) {
                accC[mt][0] = (f32x4){biasC0, biasC0, biasC0, biasC0};
                accC[mt][1] = (f32x4){biasC1, biasC1, biasC1, biasC1};
            }
#pragma unroll
            for (int kc = 0; kc < 5; ++kc) {
#pragma unroll
                for (int mt = 0; mt < 8; ++mt) {
                    bf16x8 af = ld_frag(&mlds[(mt * 16 + l15) * MSTRIDE + kc * 32 + quad * 8]);
                    accC[mt][0] = __builtin_amdgcn_mfma_f32_16x16x32_bf16(af, wc1f[kc][0], accC[mt][0], 0, 0, 0);
                    accC[mt][1] = __builtin_amdgcn_mfma_f32_16x16x32_bf16(af, wc1f[kc][1], accC[mt][1], 0, 0, 0);
                }
            }
            float pA[16], pB[16];
#pragma unroll
            for (int mt = 0; mt < 4; ++mt)
#pragma unroll
                for (int r = 0; r < 4; ++r) {
                    pA[mt * 4 + r] = silu(accC[mt][0][r]) * wcA + silu(accC[mt][1][r]) * wcB;
                    pB[mt * 4 + r] = silu(accC[mt + 4][0][r]) * wcA + silu(accC[mt + 4][1][r]) * wcB;
                }
            const float totA = butterfly16(pA, l15);
            const float totB = butterfly16(pB, l15);
            const int edge = (l15 >> 2) * 16 + quad * 4 + (l15 & 3);
            part_l[w * 128 + edge] = totA;
            part_l[w * 128 + 64 + edge] = totB;
        }
        bar_lds();   // (3) hl + part_l ready

        // ---- GEMM2: [128x128] @ Wn2(pi) -> m [128x64], direct atomic scatter ----
        {
            f32x4 acc2[8];
#pragma unroll
            for (int mt = 0; mt < 8; ++mt) acc2[mt] = (f32x4){bias2v, bias2v, bias2v, bias2v};
#pragma unroll
            for (int kc = 0; kc < 4; ++kc) {
#pragma unroll
                for (int mt = 0; mt < 8; ++mt) {
                    bf16x8 a2 = ld_frag(&hl[(mt * 16 + l15) * HSTRIDE + kc * 32 + quad * 8]);
                    acc2[mt] = __builtin_amdgcn_mfma_f32_16x16x32_bf16(a2, wn2f[kc], acc2[mt], 0, 0, 0);
                }
            }
#pragma unroll
            for (int mt = 0; mt < 8; ++mt) {
#pragma unroll
                for (int r = 0; r < 4; ++r) {
                    const int el = mt * 16 + quad * 4 + r;
                    atomicAdd(outh + (size_t)dst_l[el] * NDIM + w * 16 + l15, acc2[mt][r]);
                }
            }
        }

        // ---- coord epilogue from prefetched x regs ----
        if (tid < 128) {
            const float cw = part_l[tid] + part_l[128 + tid] + part_l[256 + tid] + part_l[384 + tid];
            const float dx = xs0 - xd0;
            const float dy = xs1 - xd1;
            const float dz = xs2 - xd2;
            float len = sqrtf(dx * dx + dy * dy + dz * dz);
            len = fmaxf(len, 1e-8f);
            const float f = cw / len;
            const int dn = dst_l[tid];
            atomicAdd(outx + (size_t)dn * 3 + 0, f * dx);
            atomicAdd(outx + (size_t)dn * 3 + 1, f * dy);
            atomicAdd(outx + (size_t)dn * 3 + 2, f * dz);
        }
    }
}

extern "C" void kernel_launch(void* const* d_in, const int* in_sizes, int n_in,
                              void* d_out, int out_size, void* d_ws, size_t ws_size,
                              hipStream_t stream) {
    const float* h    = (const float*)d_in[0];
    const float* x    = (const float*)d_in[1];
    const int*   ei   = (const int*)d_in[2];     // int32, [2, NE]
    const float* dist = (const float*)d_in[3];
    const float* We1  = (const float*)d_in[4];
    const float* be1  = (const float*)d_in[5];
    const float* We2  = (const float*)d_in[6];
    const float* be2  = (const float*)d_in[7];
    const float* Wn1  = (const float*)d_in[8];
    const float* bn1  = (const float*)d_in[9];
    const float* Wn2  = (const float*)d_in[10];
    const float* bn2  = (const float*)d_in[11];
    const float* Wc1  = (const float*)d_in[12];
    const float* bc1  = (const float*)d_in[13];
    const float* Wc2  = (const float*)d_in[14];

    float* out = (float*)d_out;
    float* ws  = (float*)d_ws;

    prep<<<2048, 256, 0, stream>>>(h, x, We2, be2, Wn1, bn1, Wc1, bc1, out, ws);
    egnn_edges<<<1024, 256, 0, stream>>>(x, ei, ei + NE, dist,
                                         We1, be1, Wn2, bn2, Wc2, ws,
                                         out, out + NH);
}